// Round 4
// baseline (446.613 us; speedup 1.0000x reference)
//
#include <hip/hip_runtime.h>

// GCSA: x(8,192,128,128) fp32 -> qkv 1x1 (MFMA) -> dw3x3 dil2 (vectorized) ->
//       channel attn -> proj folded into M -> out = M·conv(v) (fused MFMA).
// qkv_pre bf16 in ws. k0 pre-converts W to bf16; k1 64-px tiles, W direct
// from L2, swapped-operand MFMA. k45 fuses the v-conv with the output GEMM:
// conv v rows (contiguous reads) -> transposed LDS tile -> MFMA M·v_post,
// eliminating the 100 MB v_post round-trip and k5's strided column staging.

#define DIM 192
#define NH 8
#define CH 24
#define IH 128
#define IW 128
#define NPIX (IH*IW)
#define BATCH 8
#define QKVC (3*DIM)
#define PAD 200    // u16 row stride for MFMA LDS tiles (400 B)
#define SPAD 264   // u16 row stride for k2 bf16 tile (528 B, 16B-aligned)

typedef unsigned short u16;
typedef short bf16x8 __attribute__((ext_vector_type(8)));
typedef float f32x4 __attribute__((ext_vector_type(4)));

__device__ __forceinline__ float b2f(u16 u){
    unsigned v = ((unsigned)u) << 16;
    return __builtin_bit_cast(float, v);
}
__device__ __forceinline__ u16 f2b(float f){          // round-to-nearest-even
    unsigned u = __builtin_bit_cast(unsigned, f);
    u += 0x7fffu + ((u >> 16) & 1u);
    return (u16)(u >> 16);
}

// accumulate one conv row (3 taps, dilation 2) for 8 consecutive px at px0
__device__ __forceinline__ void conv_row8(const u16* __restrict__ rp, int px0,
        float w0, float w1, float w2, float* o_){
    float f[12];
    if(px0 > 0){
        unsigned u = *(const unsigned*)(rp + px0 - 2);
        f[0] = b2f((u16)u); f[1] = b2f((u16)(u >> 16));
    } else { f[0] = 0.f; f[1] = 0.f; }
    bf16x8 v = *(const bf16x8*)(rp + px0);
    #pragma unroll
    for(int j=0;j<8;j++) f[2+j] = b2f((u16)v[j]);
    if(px0 < 120){
        unsigned u = *(const unsigned*)(rp + px0 + 8);
        f[10] = b2f((u16)u); f[11] = b2f((u16)(u >> 16));
    } else { f[10] = 0.f; f[11] = 0.f; }
    #pragma unroll
    for(int i=0;i<8;i++) o_[i] += w0*f[i] + w1*f[i+2] + w2*f[i+4];
}

// ---------------------------------------------------------------------------
// K0: wqkv fp32 -> bf16 once (576x192 = 110592 elems). grid 108x256x4.
// ---------------------------------------------------------------------------
__global__ __launch_bounds__(256) void k0_wcvt(const float* __restrict__ wqkv,
        u16* __restrict__ wb){
    int i = (blockIdx.x*256 + threadIdx.x)*4;
    f32x4 v = *(const f32x4*)&wqkv[i];
    unsigned lo = ((unsigned)f2b(v[1]) << 16) | f2b(v[0]);
    unsigned hi = ((unsigned)f2b(v[3]) << 16) | f2b(v[2]);
    *(uint2*)&wb[i] = make_uint2(lo, hi);
}

// ---------------------------------------------------------------------------
// K1: qkv_pre[b][o][p] = sum_c Wqkv[o][c]*x[b][c][p].  MFMA 16x16x32 bf16.
// 64-px tile: X^T in LDS 25.6 KB. Wave w owns o-tiles w*9..w*9+8 (16 o each).
// W bf16 fragments from global (L2). Swapped operands -> 8B packed stores.
// grid (256,8).
// ---------------------------------------------------------------------------
__global__ __launch_bounds__(256) void k1_qkv(const float* __restrict__ x,
        const u16* __restrict__ wb, u16* __restrict__ qkv_pre){
    __shared__ __align__(16) u16 Xl[64*PAD];   // 25.6 KB
    const int tid = threadIdx.x;
    const int pt = blockIdx.x, b = blockIdx.y;
    const int p0 = pt*64;
    // stage X^T: Xl[px][c] (coalesced fp32 column loads, packed b128 writes)
    {
        const int px = tid & 63, grp = tid >> 6;
        const float* xb = x + (size_t)b*DIM*NPIX + p0 + px;
        #pragma unroll
        for(int cg = 0; cg < 6; cg++){
            int cb = grp*48 + cg*8;
            bf16x8 v;
            #pragma unroll
            for(int j=0;j<8;j++) v[j] = (short)f2b(xb[(size_t)(cb+j)*NPIX]);
            *(bf16x8*)&Xl[px*PAD + cb] = v;
        }
    }
    __syncthreads();
    const int lane = tid & 63, w = tid >> 6;
    const int r = lane & 15, quad = lane >> 4;
    u16* op = qkv_pre + (size_t)b*QKVC*NPIX + p0;
    for(int i = 0; i < 9; i++){
        const int ob = (w*9 + i)*16;            // o-tile base
        f32x4 acc[4];
        { f32x4 z = {0.f,0.f,0.f,0.f}; for(int j=0;j<4;j++) acc[j]=z; }
        const u16* wp = wb + (size_t)(ob + r)*DIM;
        #pragma unroll
        for(int kk = 0; kk < 6; kk++){
            const int k0 = kk*32 + quad*8;
            bf16x8 a0 = *(const bf16x8*)&wp[k0];
            #pragma unroll
            for(int ni=0; ni<4; ni++){
                bf16x8 bb = *(const bf16x8*)&Xl[(ni*16 + r)*PAD + k0];
                // swapped: D[row=px_sub][col=o_sub]
                acc[ni] = __builtin_amdgcn_mfma_f32_16x16x32_bf16(bb, a0, acc[ni], 0,0,0);
            }
        }
        // lane holds D[px = ni*16+quad*4+t][o = ob+r]
        #pragma unroll
        for(int ni=0; ni<4; ni++){
            int o = ob + r;
            int px = ni*16 + quad*4;
            f32x4 a = acc[ni];
            unsigned lo = ((unsigned)f2b(a[1]) << 16) | f2b(a[0]);
            unsigned hi = ((unsigned)f2b(a[3]) << 16) | f2b(a[2]);
            *(uint2*)&op[(size_t)o*NPIX + px] = make_uint2(lo, hi);
        }
    }
}

// ---------------------------------------------------------------------------
// K2: per (b,h): full 48x48 Gram of S=[q;k] (conv outputs, bf16) via MFMA.
// grid (32 pchunk, 8 h, 8 b).  LDS 25.3 KB.
// ---------------------------------------------------------------------------
__global__ __launch_bounds__(256) void k2_gram(const u16* __restrict__ qkv_pre,
        const float* __restrict__ wdw, float* __restrict__ G){
    __shared__ __align__(16) u16 Sl[48*SPAD];   // 25,344 B; reused as R[4][1536] f32
    const int tid = threadIdx.x;
    const int pc = blockIdx.x, h = blockIdx.y, b = blockIdx.z;
    const int lane = tid & 63, w = tid >> 6;
    const int r = lane & 15, quad = lane >> 4;
    f32x4 acc[6];
    { f32x4 z = {0.f,0.f,0.f,0.f}; for(int i=0;i<6;i++) acc[i]=z; }
    for(int chunk = 0; chunk < 2; chunk++){
        if(chunk) __syncthreads();     // prev MFMA reads of Sl done
        for(int it = 0; it < 6; it++){
            int t = tid + it*256;                 // 0..1535
            int c48 = t >> 5, oct = t & 31;
            int isK = (c48 >= CH);
            int c = isK ? (c48 - CH) : c48;
            int ch = (isK ? DIM : 0) + h*CH + c;
            const u16* base = qkv_pre + ((size_t)b*QKVC + ch)*NPIX;
            const float* wv = wdw + ch*9;
            int py = pc*4 + chunk*2 + (oct >> 4);
            int px0 = (oct & 15)*8;
            float o_[8];
            #pragma unroll
            for(int i=0;i<8;i++) o_[i]=0.f;
            #pragma unroll
            for(int ky=0;ky<3;ky++){
                int ry = py + 2*ky - 2;
                if(ry < 0 || ry >= IH) continue;
                conv_row8(base + ry*IW, px0, wv[ky*3], wv[ky*3+1], wv[ky*3+2], o_);
            }
            bf16x8 v;
            #pragma unroll
            for(int i=0;i<8;i++) v[i] = (short)f2b(o_[i]);
            *(bf16x8*)&Sl[c48*SPAD + oct*8] = v;   // col = within-chunk px idx
        }
        __syncthreads();               // Sl ready
        #pragma unroll
        for(int kk = 0; kk < 2; kk++){
            const int k0 = w*64 + kk*32 + quad*8;
            bf16x8 f0 = *(const bf16x8*)&Sl[(     r)*SPAD + k0];
            bf16x8 f1 = *(const bf16x8*)&Sl[(16 + r)*SPAD + k0];
            bf16x8 f2 = *(const bf16x8*)&Sl[(32 + r)*SPAD + k0];
            acc[0] = __builtin_amdgcn_mfma_f32_16x16x32_bf16(f0, f0, acc[0], 0,0,0);
            acc[1] = __builtin_amdgcn_mfma_f32_16x16x32_bf16(f0, f1, acc[1], 0,0,0);
            acc[2] = __builtin_amdgcn_mfma_f32_16x16x32_bf16(f0, f2, acc[2], 0,0,0);
            acc[3] = __builtin_amdgcn_mfma_f32_16x16x32_bf16(f1, f1, acc[3], 0,0,0);
            acc[4] = __builtin_amdgcn_mfma_f32_16x16x32_bf16(f1, f2, acc[4], 0,0,0);
            acc[5] = __builtin_amdgcn_mfma_f32_16x16x32_bf16(f2, f2, acc[5], 0,0,0);
        }
    }
    __syncthreads();                   // all MFMA reads of Sl done
    float* R = (float*)Sl;             // R[w][tile][lane][t]
    #pragma unroll
    for(int tile=0; tile<6; tile++)
        *(f32x4*)&R[(w*6 + tile)*256 + lane*4] = acc[tile];
    __syncthreads();
    float* Gb = G + (size_t)(b*NH + h)*48*48;
    #pragma unroll
    for(int i=0; i<6; i++){
        int idx = tid + i*256;                    // 0..1535
        int tile = idx >> 8, rem = idx & 255;
        int ln = rem >> 2, t = rem & 3;
        float s = R[idx] + R[1536 + idx] + R[2*1536 + idx] + R[3*1536 + idx];
        int ti = (tile<3) ? 0 : ((tile<5) ? 1 : 2);
        int tj = (tile<3) ? tile : ((tile<5) ? (tile-2) : 2);
        int c = ti*16 + (ln >> 4)*4 + t;
        int d = tj*16 + (ln & 15);
        atomicAdd(&Gb[c*48 + d], s);
    }
}

// ---------------------------------------------------------------------------
// K3: softmax(Gqk/(|q||k|)*T) folded with Wproj -> M[b][o][hd] (bf16). grid 8.
// norms come from the qq/kk diagonals of the 48x48 Gram.
// ---------------------------------------------------------------------------
__global__ __launch_bounds__(256) void k3_attn(const float* __restrict__ G,
        const float* __restrict__ temp, const float* __restrict__ wproj,
        u16* __restrict__ M){
    __shared__ float attn[NH][CH][CH];
    __shared__ float nq[DIM], nk[DIM];
    const int b = blockIdx.x, tid = threadIdx.x;
    const float* Gb = G + (size_t)b*NH*48*48;
    if(tid < DIM){
        int h = tid / CH, c = tid % CH;
        const float* g = Gb + (size_t)h*48*48;
        nq[tid] = fmaxf(sqrtf(g[c*48 + c]), 1e-12f);
        nk[tid] = fmaxf(sqrtf(g[(CH+c)*48 + (CH+c)]), 1e-12f);
    }
    __syncthreads();
    if(tid < DIM){
        int h = tid / CH, c = tid % CH;
        float t = temp[h];
        const float* g = Gb + (size_t)h*48*48 + c*48 + CH;   // q row c vs k cols
        float row[CH];
        float mx = -1e30f;
        #pragma unroll
        for(int d=0; d<CH; d++){
            float v = g[d] / (nq[tid]*nk[h*CH+d]) * t;
            row[d]=v; mx = fmaxf(mx,v);
        }
        float sum=0.f;
        #pragma unroll
        for(int d=0;d<CH;d++){ row[d]=expf(row[d]-mx); sum+=row[d]; }
        float inv = 1.f/sum;
        #pragma unroll
        for(int d=0;d<CH;d++) attn[h][c][d] = row[d]*inv;
    }
    __syncthreads();
    u16* Mb = M + (size_t)b*DIM*DIM;
    for(int i = tid; i < DIM*DIM; i += 256){
        int o = i / DIM, hd = i % DIM;
        int h = hd / CH, d = hd % CH;
        float s = 0.f;
        #pragma unroll
        for(int c=0;c<CH;c++)
            s += wproj[o*DIM + h*CH + c] * attn[h][c][d];
        Mb[i] = f2b(s);
    }
}

// ---------------------------------------------------------------------------
// K45: fused v-conv + output GEMM. Block = 64 px (half row) of one (b, py).
// Phase 1: conv v (rows read CONTIGUOUSLY from global) -> Vt[px][ch] bf16 LDS
//          (transposed via u32-pair writes; v_post never hits HBM).
// Phase 2: out[o][px] = sum_hd M[o][hd] * Vt[px][hd], k5's MFMA structure.
// grid (256 = 128 rows x 2 halves, 8 b). LDS 25.6 KB.
// ---------------------------------------------------------------------------
__global__ __launch_bounds__(256) void k45_out(const u16* __restrict__ qkv_pre,
        const float* __restrict__ wdw, const u16* __restrict__ M,
        float* __restrict__ out){
    __shared__ __align__(16) u16 Vt[64*PAD];   // [px_local][ch], 25.6 KB
    const int tid = threadIdx.x;
    const int half = blockIdx.x & 1, py = blockIdx.x >> 1, b = blockIdx.y;
    const int p0 = py*IW + half*64;
    // phase 1: 96 ch-pairs x 8 octets = 768 tasks, 3 per thread
    for(int it = 0; it < 3; it++){
        int t = tid + it*256;
        int chp = t >> 3, oct = t & 7;
        int px0g = half*64 + oct*8;            // global px within row
        float oo[2][8];
        #pragma unroll
        for(int j=0;j<2;j++){
            int ch = 2*chp + j;
            const u16* base = qkv_pre + ((size_t)b*QKVC + 2*DIM + ch)*NPIX;
            const float* wv = wdw + (2*DIM + ch)*9;
            #pragma unroll
            for(int i=0;i<8;i++) oo[j][i]=0.f;
            #pragma unroll
            for(int ky=0;ky<3;ky++){
                int ry = py + 2*ky - 2;
                if(ry < 0 || ry >= IH) continue;
                conv_row8(base + ry*IW, px0g, wv[ky*3], wv[ky*3+1], wv[ky*3+2], oo[j]);
            }
        }
        #pragma unroll
        for(int i=0;i<8;i++){
            unsigned pk = (unsigned)f2b(oo[0][i]) | ((unsigned)f2b(oo[1][i]) << 16);
            *(unsigned*)&Vt[(oct*8+i)*PAD + 2*chp] = pk;
        }
    }
    __syncthreads();
    // phase 2: MFMA  D[px][o], wave w owns o-tiles w*3..w*3+2
    const int lane = tid & 63, w = tid >> 6;
    const int r = lane & 15, quad = lane >> 4;
    const u16* Mb = M + (size_t)b*DIM*DIM;
    float* op = out + (size_t)b*DIM*NPIX + p0;
    for(int i = 0; i < 3; i++){
        const int ob = (w*3 + i)*16;
        f32x4 acc[4];
        { f32x4 z = {0.f,0.f,0.f,0.f}; for(int j=0;j<4;j++) acc[j]=z; }
        const u16* mp = Mb + (size_t)(ob + r)*DIM;
        #pragma unroll
        for(int kk = 0; kk < 6; kk++){
            const int k0 = kk*32 + quad*8;
            bf16x8 a0 = *(const bf16x8*)&mp[k0];
            #pragma unroll
            for(int ni=0; ni<4; ni++){
                bf16x8 bb = *(const bf16x8*)&Vt[(ni*16 + r)*PAD + k0];
                acc[ni] = __builtin_amdgcn_mfma_f32_16x16x32_bf16(bb, a0, acc[ni], 0,0,0);
            }
        }
        #pragma unroll
        for(int ni=0; ni<4; ni++)
            *(f32x4*)&op[(size_t)(ob + r)*NPIX + ni*16 + quad*4] = acc[ni];
    }
}

// ---------------------------------------------------------------------------
extern "C" void kernel_launch(void* const* d_in, const int* in_sizes, int n_in,
                              void* d_out, int out_size, void* d_ws, size_t ws_size,
                              hipStream_t stream){
    const float* x     = (const float*)d_in[0];
    const float* wqkv  = (const float*)d_in[1];
    const float* wdw   = (const float*)d_in[2];
    const float* wproj = (const float*)d_in[3];
    const float* temp  = (const float*)d_in[4];
    float* out = (float*)d_out;

    char* ws = (char*)d_ws;
    u16* qkv_pre = (u16*)ws;                                     // 151 MB
    size_t off = (size_t)BATCH*QKVC*NPIX*sizeof(u16);
    float* G  = (float*)(ws + off); off += (size_t)BATCH*NH*48*48*4;
    u16* M    = (u16*)(ws + off);   off += (size_t)BATCH*DIM*DIM*2;
    u16* wb   = (u16*)(ws + off);   off += (size_t)QKVC*DIM*2;

    hipMemsetAsync(G, 0, (size_t)BATCH*NH*48*48*sizeof(float), stream);

    k0_wcvt<<<108, 256, 0, stream>>>(wqkv, wb);
    k1_qkv <<<dim3(256, BATCH), 256, 0, stream>>>(x, wb, qkv_pre);
    k2_gram<<<dim3(32, NH, BATCH), 256, 0, stream>>>(qkv_pre, wdw, G);
    k3_attn<<<BATCH, 256, 0, stream>>>(G, temp, wproj, M);
    k45_out<<<dim3(256, BATCH), 256, 0, stream>>>(qkv_pre, wdw, M, out);
}

// Round 5
// 431.702 us; speedup vs baseline: 1.0345x; 1.0345x over previous
//
#include <hip/hip_runtime.h>

// GCSA: x(8,192,128,128) fp32 -> qkv 1x1 (MFMA) -> dw3x3 dil2 (vectorized) ->
//       channel attn -> proj folded into M -> out = M·conv(v) (fused MFMA).
// qkv_pre bf16 in ws. k0 pre-converts W to bf16; k1 64-px tiles, W direct
// from L2, swapped-operand MFMA. k45 fuses v-conv with the output GEMM:
// 4 rows/block (parity-ordered) + XCD-band swizzle so conv halo rows hit the
// local L2; M fragments hoisted to registers across the 4 sub-tiles.

#define DIM 192
#define NH 8
#define CH 24
#define IH 128
#define IW 128
#define NPIX (IH*IW)
#define BATCH 8
#define QKVC (3*DIM)
#define PAD 200    // u16 row stride for MFMA LDS tiles (400 B)
#define SPAD 264   // u16 row stride for k2 bf16 tile (528 B, 16B-aligned)

typedef unsigned short u16;
typedef short bf16x8 __attribute__((ext_vector_type(8)));
typedef float f32x4 __attribute__((ext_vector_type(4)));

__device__ __forceinline__ float b2f(u16 u){
    unsigned v = ((unsigned)u) << 16;
    return __builtin_bit_cast(float, v);
}
__device__ __forceinline__ u16 f2b(float f){          // round-to-nearest-even
    unsigned u = __builtin_bit_cast(unsigned, f);
    u += 0x7fffu + ((u >> 16) & 1u);
    return (u16)(u >> 16);
}

// accumulate one conv row (3 taps, dilation 2) for 8 consecutive px at px0
__device__ __forceinline__ void conv_row8(const u16* __restrict__ rp, int px0,
        float w0, float w1, float w2, float* o_){
    float f[12];
    if(px0 > 0){
        unsigned u = *(const unsigned*)(rp + px0 - 2);
        f[0] = b2f((u16)u); f[1] = b2f((u16)(u >> 16));
    } else { f[0] = 0.f; f[1] = 0.f; }
    bf16x8 v = *(const bf16x8*)(rp + px0);
    #pragma unroll
    for(int j=0;j<8;j++) f[2+j] = b2f((u16)v[j]);
    if(px0 < 120){
        unsigned u = *(const unsigned*)(rp + px0 + 8);
        f[10] = b2f((u16)u); f[11] = b2f((u16)(u >> 16));
    } else { f[10] = 0.f; f[11] = 0.f; }
    #pragma unroll
    for(int i=0;i<8;i++) o_[i] += w0*f[i] + w1*f[i+2] + w2*f[i+4];
}

// ---------------------------------------------------------------------------
// K0: wqkv fp32 -> bf16 once (576x192 = 110592 elems). grid 108x256x4.
// ---------------------------------------------------------------------------
__global__ __launch_bounds__(256) void k0_wcvt(const float* __restrict__ wqkv,
        u16* __restrict__ wb){
    int i = (blockIdx.x*256 + threadIdx.x)*4;
    f32x4 v = *(const f32x4*)&wqkv[i];
    unsigned lo = ((unsigned)f2b(v[1]) << 16) | f2b(v[0]);
    unsigned hi = ((unsigned)f2b(v[3]) << 16) | f2b(v[2]);
    *(uint2*)&wb[i] = make_uint2(lo, hi);
}

// ---------------------------------------------------------------------------
// K1: qkv_pre[b][o][p] = sum_c Wqkv[o][c]*x[b][c][p].  MFMA 16x16x32 bf16.
// 64-px tile: X^T in LDS 25.6 KB. Wave w owns o-tiles w*9..w*9+8 (16 o each).
// W bf16 fragments from global (L2). Swapped operands -> 8B packed stores.
// grid (256,8).
// ---------------------------------------------------------------------------
__global__ __launch_bounds__(256) void k1_qkv(const float* __restrict__ x,
        const u16* __restrict__ wb, u16* __restrict__ qkv_pre){
    __shared__ __align__(16) u16 Xl[64*PAD];   // 25.6 KB
    const int tid = threadIdx.x;
    const int pt = blockIdx.x, b = blockIdx.y;
    const int p0 = pt*64;
    // stage X^T: Xl[px][c] (coalesced fp32 column loads, packed b128 writes)
    {
        const int px = tid & 63, grp = tid >> 6;
        const float* xb = x + (size_t)b*DIM*NPIX + p0 + px;
        #pragma unroll
        for(int cg = 0; cg < 6; cg++){
            int cb = grp*48 + cg*8;
            bf16x8 v;
            #pragma unroll
            for(int j=0;j<8;j++) v[j] = (short)f2b(xb[(size_t)(cb+j)*NPIX]);
            *(bf16x8*)&Xl[px*PAD + cb] = v;
        }
    }
    __syncthreads();
    const int lane = tid & 63, w = tid >> 6;
    const int r = lane & 15, quad = lane >> 4;
    u16* op = qkv_pre + (size_t)b*QKVC*NPIX + p0;
    for(int i = 0; i < 9; i++){
        const int ob = (w*9 + i)*16;            // o-tile base
        f32x4 acc[4];
        { f32x4 z = {0.f,0.f,0.f,0.f}; for(int j=0;j<4;j++) acc[j]=z; }
        const u16* wp = wb + (size_t)(ob + r)*DIM;
        #pragma unroll
        for(int kk = 0; kk < 6; kk++){
            const int k0 = kk*32 + quad*8;
            bf16x8 a0 = *(const bf16x8*)&wp[k0];
            #pragma unroll
            for(int ni=0; ni<4; ni++){
                bf16x8 bb = *(const bf16x8*)&Xl[(ni*16 + r)*PAD + k0];
                // swapped: D[row=px_sub][col=o_sub]
                acc[ni] = __builtin_amdgcn_mfma_f32_16x16x32_bf16(bb, a0, acc[ni], 0,0,0);
            }
        }
        // lane holds D[px = ni*16+quad*4+t][o = ob+r]
        #pragma unroll
        for(int ni=0; ni<4; ni++){
            int o = ob + r;
            int px = ni*16 + quad*4;
            f32x4 a = acc[ni];
            unsigned lo = ((unsigned)f2b(a[1]) << 16) | f2b(a[0]);
            unsigned hi = ((unsigned)f2b(a[3]) << 16) | f2b(a[2]);
            *(uint2*)&op[(size_t)o*NPIX + px] = make_uint2(lo, hi);
        }
    }
}

// ---------------------------------------------------------------------------
// K2: per (b,h): full 48x48 Gram of S=[q;k] (conv outputs, bf16) via MFMA.
// XCD-band swizzle on pc: same-XCD blocks get contiguous 4-row chunks so the
// conv's 2x row halo hits the local L2. grid (32 pchunk, 8 h, 8 b).
// ---------------------------------------------------------------------------
__global__ __launch_bounds__(256) void k2_gram(const u16* __restrict__ qkv_pre,
        const float* __restrict__ wdw, float* __restrict__ G){
    __shared__ __align__(16) u16 Sl[48*SPAD];   // 25,344 B; reused as R[4][1536] f32
    const int tid = threadIdx.x;
    const int bx = blockIdx.x, h = blockIdx.y, b = blockIdx.z;
    const int pc = 4*(bx & 7) + (bx >> 3);      // XCD (flat%8=bx%8) gets pc 4x..4x+3
    const int lane = tid & 63, w = tid >> 6;
    const int r = lane & 15, quad = lane >> 4;
    f32x4 acc[6];
    { f32x4 z = {0.f,0.f,0.f,0.f}; for(int i=0;i<6;i++) acc[i]=z; }
    for(int chunk = 0; chunk < 2; chunk++){
        if(chunk) __syncthreads();     // prev MFMA reads of Sl done
        for(int it = 0; it < 6; it++){
            int t = tid + it*256;                 // 0..1535
            int c48 = t >> 5, oct = t & 31;
            int isK = (c48 >= CH);
            int c = isK ? (c48 - CH) : c48;
            int ch = (isK ? DIM : 0) + h*CH + c;
            const u16* base = qkv_pre + ((size_t)b*QKVC + ch)*NPIX;
            const float* wv = wdw + ch*9;
            int py = pc*4 + chunk*2 + (oct >> 4);
            int px0 = (oct & 15)*8;
            float o_[8];
            #pragma unroll
            for(int i=0;i<8;i++) o_[i]=0.f;
            #pragma unroll
            for(int ky=0;ky<3;ky++){
                int ry = py + 2*ky - 2;
                if(ry < 0 || ry >= IH) continue;
                conv_row8(base + ry*IW, px0, wv[ky*3], wv[ky*3+1], wv[ky*3+2], o_);
            }
            bf16x8 v;
            #pragma unroll
            for(int i=0;i<8;i++) v[i] = (short)f2b(o_[i]);
            *(bf16x8*)&Sl[c48*SPAD + oct*8] = v;   // col = within-chunk px idx
        }
        __syncthreads();               // Sl ready
        #pragma unroll
        for(int kk = 0; kk < 2; kk++){
            const int k0 = w*64 + kk*32 + quad*8;
            bf16x8 f0 = *(const bf16x8*)&Sl[(     r)*SPAD + k0];
            bf16x8 f1 = *(const bf16x8*)&Sl[(16 + r)*SPAD + k0];
            bf16x8 f2 = *(const bf16x8*)&Sl[(32 + r)*SPAD + k0];
            acc[0] = __builtin_amdgcn_mfma_f32_16x16x32_bf16(f0, f0, acc[0], 0,0,0);
            acc[1] = __builtin_amdgcn_mfma_f32_16x16x32_bf16(f0, f1, acc[1], 0,0,0);
            acc[2] = __builtin_amdgcn_mfma_f32_16x16x32_bf16(f0, f2, acc[2], 0,0,0);
            acc[3] = __builtin_amdgcn_mfma_f32_16x16x32_bf16(f1, f1, acc[3], 0,0,0);
            acc[4] = __builtin_amdgcn_mfma_f32_16x16x32_bf16(f1, f2, acc[4], 0,0,0);
            acc[5] = __builtin_amdgcn_mfma_f32_16x16x32_bf16(f2, f2, acc[5], 0,0,0);
        }
    }
    __syncthreads();                   // all MFMA reads of Sl done
    float* R = (float*)Sl;             // R[w][tile][lane][t]
    #pragma unroll
    for(int tile=0; tile<6; tile++)
        *(f32x4*)&R[(w*6 + tile)*256 + lane*4] = acc[tile];
    __syncthreads();
    float* Gb = G + (size_t)(b*NH + h)*48*48;
    #pragma unroll
    for(int i=0; i<6; i++){
        int idx = tid + i*256;                    // 0..1535
        int tile = idx >> 8, rem = idx & 255;
        int ln = rem >> 2, t = rem & 3;
        float s = R[idx] + R[1536 + idx] + R[2*1536 + idx] + R[3*1536 + idx];
        int ti = (tile<3) ? 0 : ((tile<5) ? 1 : 2);
        int tj = (tile<3) ? tile : ((tile<5) ? (tile-2) : 2);
        int c = ti*16 + (ln >> 4)*4 + t;
        int d = tj*16 + (ln & 15);
        atomicAdd(&Gb[c*48 + d], s);
    }
}

// ---------------------------------------------------------------------------
// K3: softmax(Gqk/(|q||k|)*T) folded with Wproj -> M[b][o][hd] (bf16). grid 8.
// norms come from the qq/kk diagonals of the 48x48 Gram.
// ---------------------------------------------------------------------------
__global__ __launch_bounds__(256) void k3_attn(const float* __restrict__ G,
        const float* __restrict__ temp, const float* __restrict__ wproj,
        u16* __restrict__ M){
    __shared__ float attn[NH][CH][CH];
    __shared__ float nq[DIM], nk[DIM];
    const int b = blockIdx.x, tid = threadIdx.x;
    const float* Gb = G + (size_t)b*NH*48*48;
    if(tid < DIM){
        int h = tid / CH, c = tid % CH;
        const float* g = Gb + (size_t)h*48*48;
        nq[tid] = fmaxf(sqrtf(g[c*48 + c]), 1e-12f);
        nk[tid] = fmaxf(sqrtf(g[(CH+c)*48 + (CH+c)]), 1e-12f);
    }
    __syncthreads();
    if(tid < DIM){
        int h = tid / CH, c = tid % CH;
        float t = temp[h];
        const float* g = Gb + (size_t)h*48*48 + c*48 + CH;   // q row c vs k cols
        float row[CH];
        float mx = -1e30f;
        #pragma unroll
        for(int d=0; d<CH; d++){
            float v = g[d] / (nq[tid]*nk[h*CH+d]) * t;
            row[d]=v; mx = fmaxf(mx,v);
        }
        float sum=0.f;
        #pragma unroll
        for(int d=0;d<CH;d++){ row[d]=expf(row[d]-mx); sum+=row[d]; }
        float inv = 1.f/sum;
        #pragma unroll
        for(int d=0;d<CH;d++) attn[h][c][d] = row[d]*inv;
    }
    __syncthreads();
    u16* Mb = M + (size_t)b*DIM*DIM;
    for(int i = tid; i < DIM*DIM; i += 256){
        int o = i / DIM, hd = i % DIM;
        int h = hd / CH, d = hd % CH;
        float s = 0.f;
        #pragma unroll
        for(int c=0;c<CH;c++)
            s += wproj[o*DIM + h*CH + c] * attn[h][c][d];
        Mb[i] = f2b(s);
    }
}

// ---------------------------------------------------------------------------
// K45: fused v-conv + output GEMM, 4 rows per block.
// Block = (strip of 4 rows, half of 64 px, b).  XCD-band swizzle: XCD x owns
// strips 4x..4x+3 (rows 16x..16x+15) -> conv halo rows hit local L2.
// Rows processed in parity order (0,2,1,3) so shared taps are 1 sub-tile
// apart.  Per sub-tile: conv 192 ch -> Vt[px][ch] LDS -> MFMA M·Vt -> out.
// M fragments hoisted to registers (identical across sub-tiles).
// grid (64, 8). LDS 25.6 KB.
// ---------------------------------------------------------------------------
__global__ __launch_bounds__(256) void k45_out(const u16* __restrict__ qkv_pre,
        const float* __restrict__ wdw, const u16* __restrict__ M,
        float* __restrict__ out){
    __shared__ __align__(16) u16 Vt[64*PAD];   // [px_local][ch], 25.6 KB
    const int tid = threadIdx.x;
    const int bx = blockIdx.x, b = blockIdx.y;
    // wg->XCD = flat%8 = bx%8 (64*b term == 0 mod 8): give XCD x contiguous strips
    const int strip = 4*(bx & 7) + (bx >> 4);   // [0,32), bijective
    const int half  = (bx >> 3) & 1;
    const int r0 = strip*4;
    const int lane = tid & 63, w = tid >> 6;
    const int r = lane & 15, quad = lane >> 4;
    // hoist M fragments: wave w owns o-tiles w*3..w*3+2 (same for all rows)
    bf16x8 mreg[3][6];
    {
        const u16* Mb = M + (size_t)b*DIM*DIM;
        #pragma unroll
        for(int i=0;i<3;i++){
            const u16* mp = Mb + (size_t)((w*3+i)*16 + r)*DIM;
            #pragma unroll
            for(int kk=0;kk<6;kk++)
                mreg[i][kk] = *(const bf16x8*)&mp[kk*32 + quad*8];
        }
    }
    for(int ri = 0; ri < 4; ri++){
        const int py = r0 + ((ri & 1) << 1) + (ri >> 1);   // 0,2,1,3
        if(ri) __syncthreads();        // prev sub-tile's MFMA reads done
        // phase 1: conv 96 ch-pairs x 8 octets = 768 tasks, 3 per thread
        for(int it = 0; it < 3; it++){
            int t = tid + it*256;
            int chp = t >> 3, oct = t & 7;
            int px0g = half*64 + oct*8;        // global px within row
            float oo[2][8];
            #pragma unroll
            for(int j=0;j<2;j++){
                int ch = 2*chp + j;
                const u16* base = qkv_pre + ((size_t)b*QKVC + 2*DIM + ch)*NPIX;
                const float* wv = wdw + (2*DIM + ch)*9;
                #pragma unroll
                for(int i=0;i<8;i++) oo[j][i]=0.f;
                #pragma unroll
                for(int ky=0;ky<3;ky++){
                    int ry = py + 2*ky - 2;
                    if(ry < 0 || ry >= IH) continue;
                    conv_row8(base + ry*IW, px0g, wv[ky*3], wv[ky*3+1], wv[ky*3+2], oo[j]);
                }
            }
            #pragma unroll
            for(int i=0;i<8;i++){
                unsigned pk = (unsigned)f2b(oo[0][i]) | ((unsigned)f2b(oo[1][i]) << 16);
                *(unsigned*)&Vt[(oct*8+i)*PAD + 2*chp] = pk;
            }
        }
        __syncthreads();
        // phase 2: MFMA  D[px][o]
        float* op = out + (size_t)b*DIM*NPIX + py*IW + half*64;
        #pragma unroll
        for(int i = 0; i < 3; i++){
            const int ob = (w*3 + i)*16;
            f32x4 acc[4];
            { f32x4 z = {0.f,0.f,0.f,0.f}; for(int j=0;j<4;j++) acc[j]=z; }
            #pragma unroll
            for(int kk = 0; kk < 6; kk++){
                const int k0 = kk*32 + quad*8;
                #pragma unroll
                for(int ni=0; ni<4; ni++){
                    bf16x8 bb = *(const bf16x8*)&Vt[(ni*16 + r)*PAD + k0];
                    acc[ni] = __builtin_amdgcn_mfma_f32_16x16x32_bf16(bb, mreg[i][kk], acc[ni], 0,0,0);
                }
            }
            #pragma unroll
            for(int ni=0; ni<4; ni++)
                *(f32x4*)&op[(size_t)(ob + r)*NPIX + ni*16 + quad*4] = acc[ni];
        }
    }
}

// ---------------------------------------------------------------------------
extern "C" void kernel_launch(void* const* d_in, const int* in_sizes, int n_in,
                              void* d_out, int out_size, void* d_ws, size_t ws_size,
                              hipStream_t stream){
    const float* x     = (const float*)d_in[0];
    const float* wqkv  = (const float*)d_in[1];
    const float* wdw   = (const float*)d_in[2];
    const float* wproj = (const float*)d_in[3];
    const float* temp  = (const float*)d_in[4];
    float* out = (float*)d_out;

    char* ws = (char*)d_ws;
    u16* qkv_pre = (u16*)ws;                                     // 151 MB
    size_t off = (size_t)BATCH*QKVC*NPIX*sizeof(u16);
    float* G  = (float*)(ws + off); off += (size_t)BATCH*NH*48*48*4;
    u16* M    = (u16*)(ws + off);   off += (size_t)BATCH*DIM*DIM*2;
    u16* wb   = (u16*)(ws + off);   off += (size_t)QKVC*DIM*2;

    hipMemsetAsync(G, 0, (size_t)BATCH*NH*48*48*sizeof(float), stream);

    k0_wcvt<<<108, 256, 0, stream>>>(wqkv, wb);
    k1_qkv <<<dim3(256, BATCH), 256, 0, stream>>>(x, wb, qkv_pre);
    k2_gram<<<dim3(32, NH, BATCH), 256, 0, stream>>>(qkv_pre, wdw, G);
    k3_attn<<<BATCH, 256, 0, stream>>>(G, temp, wproj, M);
    k45_out<<<dim3(64, BATCH), 256, 0, stream>>>(qkv_pre, wdw, M, out);
}